// Round 4
// baseline (368.968 us; speedup 1.0000x reference)
//
#include <hip/hip_runtime.h>
#include <hip/hip_bf16.h>
#include <math.h>

// Problem constants
#define B_ 8
#define R_ 1024
#define D_ 256
#define H_ 8
#define L_ 2
#define E_ 32768
#define FF_ 1024
#define NEGV (-1000000000.0f)

typedef short bf16x8 __attribute__((ext_vector_type(8)));
typedef float f32x4 __attribute__((ext_vector_type(4)));

__device__ __forceinline__ unsigned short f2b(float f){
  unsigned int u = __float_as_uint(f);
  u += 0x7fffu + ((u >> 16) & 1u);   // round-to-nearest-even
  return (unsigned short)(u >> 16);
}

#define ASYNC_COPY16(gp, lp) \
  __builtin_amdgcn_global_load_lds((const __attribute__((address_space(1))) void*)(gp), \
                                   (__attribute__((address_space(3))) void*)(lp), 16, 0, 0)

// ---------------- mask construction ----------------

// detect whether keep_mask is 1-byte bools (flag=1) or int32 (flag=0)
__global__ void detect_bool(const unsigned char* __restrict__ km, int* __restrict__ flag){
  int i = blockIdx.x*256 + threadIdx.x;           // [0, B*E)
  int hit = ((i & 3) != 0) && (km[i] != 0);
  if (__ballot(hit) != 0ull && (threadIdx.x & 63) == 0) atomicOr(flag, 1);
}

__global__ void mask_fill(float* __restrict__ mask){
  size_t i = ((size_t)blockIdx.x*256 + threadIdx.x)*4;   // over B*R*R
  int row = (int)((i >> 10) & 1023);
  int col = (int)(i & 1023);
  float4 v;
  v.x = (row == col+0) ? 0.0f : NEGV;
  v.y = (row == col+1) ? 0.0f : NEGV;
  v.z = (row == col+2) ? 0.0f : NEGV;
  v.w = (row == col+3) ? 0.0f : NEGV;
  *(float4*)&mask[i] = v;
}

__device__ __forceinline__ int keep_of(const unsigned char* km, const int* flag, int tid){
  return flag[0] ? (int)km[tid] : (int)km[(size_t)tid*4];   // byte-bool vs int32 low byte
}

__global__ void edge_base(const int* __restrict__ ei, const unsigned char* __restrict__ km,
                          const int* __restrict__ flag, float* __restrict__ mask){
  int tid = blockIdx.x*256 + threadIdx.x;   // < B*E
  int b = tid >> 15, e = tid & (E_-1);
  if (keep_of(km, flag, tid)){
    int src = ei[(size_t)b*2*E_ + e];
    int dst = ei[(size_t)b*2*E_ + E_ + e];
    mask[((size_t)b*R_ + src)*R_ + dst] = 0.0f;
  }
}

__global__ void edge_bias(const int* __restrict__ ei, const int* __restrict__ rid,
                          const unsigned char* __restrict__ km, const int* __restrict__ flag,
                          const float* __restrict__ rb, float* __restrict__ mask){
  int tid = blockIdx.x*256 + threadIdx.x;
  int b = tid >> 15, e = tid & (E_-1);
  if (keep_of(km, flag, tid)){
    int src = ei[(size_t)b*2*E_ + e];
    int dst = ei[(size_t)b*2*E_ + E_ + e];
    atomicAdd(&mask[((size_t)b*R_ + src)*R_ + dst], rb[rid[tid]]);
  }
}

// ---------------- dtype convert ----------------

__global__ void cvt_bf16(const float* __restrict__ src, unsigned short* __restrict__ dst, int n){
  int i = (blockIdx.x*256 + threadIdx.x)*4;
  if (i >= n) return;
  float4 v = *(const float4*)&src[i];
  ushort4 o;
  o.x = f2b(v.x); o.y = f2b(v.y); o.z = f2b(v.z); o.w = f2b(v.w);
  *(ushort4*)&dst[i] = o;
}

// ---------------- GEMM: C[M,N] = A[M,K] * B[N,K]^T  (both bf16 row-major, K-contig) ----
// MODE 0: bf16 out, +bias       (QKV)
// MODE 1: f32  out, +bias       (Wo / W2 pre-residual)
// MODE 2: bf16 out, gelu(+bias) (W1)
template<int MODE>
__global__ __launch_bounds__(256) void gemm_bt(const unsigned short* __restrict__ A,
    const unsigned short* __restrict__ Bw, const float* __restrict__ bias,
    void* __restrict__ Cout, int M, int N, int K)
{
  __shared__ unsigned short As[128*32];
  __shared__ unsigned short Bs[128*32];
  const int nb = N >> 7;
  const int bm = blockIdx.x / nb, bn = blockIdx.x % nb;
  const int m0 = bm << 7, n0 = bn << 7;
  const int t = threadIdx.x, lane = t & 63, wid = t >> 6;
  const int wr = wid >> 1, wc = wid & 1;
  const int c = lane & 15, g = lane >> 4;

  f32x4 zz = {0.f,0.f,0.f,0.f};
  f32x4 acc[4][4];
  #pragma unroll
  for (int mi=0; mi<4; mi++)
    #pragma unroll
    for (int ni=0; ni<4; ni++) acc[mi][ni] = zz;

  for (int k0 = 0; k0 < K; k0 += 32){
    __syncthreads();
    #pragma unroll
    for (int it=0; it<2; ++it){
      int chunk = wid*2 + it;          // 0..7, wave-uniform
      int idx = chunk*64 + lane;       // 0..511
      int row = idx >> 2, seg = idx & 3;
      ASYNC_COPY16(A  + (size_t)(m0+row)*K + k0 + seg*8, &As[chunk*512]);
      ASYNC_COPY16(Bw + (size_t)(n0+row)*K + k0 + seg*8, &Bs[chunk*512]);
    }
    __syncthreads();
    bf16x8 af[4], bfr[4];
    #pragma unroll
    for (int mi=0; mi<4; mi++) af[mi]  = *(const bf16x8*)&As[(wr*64 + mi*16 + c)*32 + g*8];
    #pragma unroll
    for (int ni=0; ni<4; ni++) bfr[ni] = *(const bf16x8*)&Bs[(wc*64 + ni*16 + c)*32 + g*8];
    #pragma unroll
    for (int mi=0; mi<4; mi++)
      #pragma unroll
      for (int ni=0; ni<4; ni++)
        acc[mi][ni] = __builtin_amdgcn_mfma_f32_16x16x32_bf16(af[mi], bfr[ni], acc[mi][ni], 0,0,0);
  }

  #pragma unroll
  for (int mi=0; mi<4; mi++){
    #pragma unroll
    for (int ni=0; ni<4; ni++){
      int col = n0 + wc*64 + ni*16 + c;
      float bv = bias[col];
      #pragma unroll
      for (int r=0; r<4; r++){
        int row = m0 + wr*64 + mi*16 + 4*g + r;
        float v = acc[mi][ni][r] + bv;
        if (MODE == 2) v = 0.5f*v*(1.0f + erff(v*0.70710678f));
        if (MODE == 1) ((float*)Cout)[(size_t)row*N + col] = v;
        else           ((unsigned short*)Cout)[(size_t)row*N + col] = f2b(v);
      }
    }
  }
}

// ---------------- fused flash attention (per (b,h,qtile=128 rows)) ----------------
__global__ __launch_bounds__(256) void attn_kernel(const unsigned short* __restrict__ qkv,
    const float* __restrict__ mask, unsigned short* __restrict__ aout)
{
  __shared__ unsigned short Klds[128*40];   // K tile [kv][d], row stride 40 (pad)
  __shared__ unsigned short VT[32*136];     // V^T tile [d][kv], row stride 136 (pad)
  __shared__ unsigned short P[4*32*136];    // per-wave P tile [32 q][128 kv] stride 136
  const int blk = blockIdx.x;
  const int qt = blk & 7, h = (blk >> 3) & 7, b = blk >> 6;
  const int t = threadIdx.x, lane = t & 63, wid = t >> 6;
  const int c = lane & 15, g = lane >> 4;
  const int q0 = qt*128;
  const size_t qbase = (size_t)b*R_*768;
  const float scale = 0.17677669529663689f;   // 1/sqrt(32)

  // Q fragments (rows q0+wid*32+fr*16+c, k=d=8g..8g+7), reused across all KV tiles
  bf16x8 qf[2];
  #pragma unroll
  for (int fr=0; fr<2; ++fr){
    int qr = q0 + wid*32 + fr*16 + c;
    qf[fr] = *(const bf16x8*)&qkv[qbase + (size_t)qr*768 + h*32 + g*8];
  }

  f32x4 z4 = {0.f,0.f,0.f,0.f};
  f32x4 oacc[2][2];
  float mrun[2][4], lrun[2][4];
  #pragma unroll
  for (int fr=0; fr<2; ++fr){
    oacc[fr][0] = z4; oacc[fr][1] = z4;
    #pragma unroll
    for (int r=0; r<4; r++){ mrun[fr][r] = -1e30f; lrun[fr][r] = 0.f; }
  }
  unsigned short* Pw = &P[wid*32*136];

  for (int kt=0; kt<8; ++kt){
    const int kv0 = kt*128;
    __syncthreads();
    // stage K [128][32] -> Klds (padded rows of 40)
    #pragma unroll
    for (int it=0; it<2; ++it){
      int idx = it*256 + t, row = idx >> 2, seg = idx & 3;
      uint4 kd = *(const uint4*)&qkv[qbase + (size_t)(kv0+row)*768 + 256 + h*32 + seg*8];
      *(uint4*)&Klds[row*40 + seg*8] = kd;
    }
    // stage V transposed: VT[d][kv]
    {
      int d = t & 31, rb8 = t >> 5;   // rows rb8*16 .. +15
      __align__(16) unsigned short tv[16];
      #pragma unroll
      for (int j=0; j<16; j++)
        tv[j] = qkv[qbase + (size_t)(kv0 + rb8*16 + j)*768 + 512 + h*32 + d];
      *(uint4*)&VT[d*136 + rb8*16]     = *(const uint4*)&tv[0];
      *(uint4*)&VT[d*136 + rb8*16 + 8] = *(const uint4*)&tv[8];
    }
    __syncthreads();

    // S = Q*K^T
    f32x4 sacc[2][8];
    #pragma unroll
    for (int fc=0; fc<8; ++fc){
      bf16x8 kb = *(const bf16x8*)&Klds[(fc*16 + c)*40 + g*8];
      sacc[0][fc] = __builtin_amdgcn_mfma_f32_16x16x32_bf16(qf[0], kb, z4, 0,0,0);
      sacc[1][fc] = __builtin_amdgcn_mfma_f32_16x16x32_bf16(qf[1], kb, z4, 0,0,0);
    }
    // scale + mask
    #pragma unroll
    for (int fr=0; fr<2; ++fr)
      #pragma unroll
      for (int fc=0; fc<8; ++fc)
        #pragma unroll
        for (int r=0; r<4; r++){
          int qr = q0 + wid*32 + fr*16 + 4*g + r;
          float mv = mask[((size_t)b*R_ + qr)*R_ + kv0 + fc*16 + c];
          sacc[fr][fc][r] = sacc[fr][fc][r]*scale + mv;
        }
    // online softmax (per q-row: lane-local over 8 frag cols, then 16-lane xor-reduce)
    #pragma unroll
    for (int fr=0; fr<2; ++fr)
      #pragma unroll
      for (int r=0; r<4; r++){
        float mx = sacc[fr][0][r];
        #pragma unroll
        for (int fc=1; fc<8; ++fc) mx = fmaxf(mx, sacc[fr][fc][r]);
        mx = fmaxf(mx, __shfl_xor(mx, 1));
        mx = fmaxf(mx, __shfl_xor(mx, 2));
        mx = fmaxf(mx, __shfl_xor(mx, 4));
        mx = fmaxf(mx, __shfl_xor(mx, 8));
        float mnew  = fmaxf(mrun[fr][r], mx);
        float alpha = __expf(mrun[fr][r] - mnew);
        float sum = 0.f;
        #pragma unroll
        for (int fc=0; fc<8; ++fc){
          float pv = __expf(sacc[fr][fc][r] - mnew);
          sacc[fr][fc][r] = pv;
          sum += pv;
        }
        sum += __shfl_xor(sum, 1); sum += __shfl_xor(sum, 2);
        sum += __shfl_xor(sum, 4); sum += __shfl_xor(sum, 8);
        lrun[fr][r] = lrun[fr][r]*alpha + sum;
        mrun[fr][r] = mnew;
        oacc[fr][0][r] *= alpha;
        oacc[fr][1][r] *= alpha;
      }
    // write P (bf16) to this wave's private LDS region
    #pragma unroll
    for (int fr=0; fr<2; ++fr)
      #pragma unroll
      for (int fc=0; fc<8; ++fc)
        #pragma unroll
        for (int r=0; r<4; r++)
          Pw[(fr*16 + 4*g + r)*136 + fc*16 + c] = f2b(sacc[fr][fc][r]);
    // O += P*V  (A-frags from Pw, B-frags from VT)
    #pragma unroll
    for (int ks=0; ks<4; ++ks){
      bf16x8 pa0 = *(const bf16x8*)&Pw[(c)*136      + ks*32 + g*8];
      bf16x8 pa1 = *(const bf16x8*)&Pw[(16 + c)*136 + ks*32 + g*8];
      #pragma unroll
      for (int dg=0; dg<2; ++dg){
        bf16x8 vb = *(const bf16x8*)&VT[(dg*16 + c)*136 + ks*32 + g*8];
        oacc[0][dg] = __builtin_amdgcn_mfma_f32_16x16x32_bf16(pa0, vb, oacc[0][dg], 0,0,0);
        oacc[1][dg] = __builtin_amdgcn_mfma_f32_16x16x32_bf16(pa1, vb, oacc[1][dg], 0,0,0);
      }
    }
  }
  // epilogue: normalize and store bf16 [b][q][h*32+d]
  #pragma unroll
  for (int fr=0; fr<2; ++fr)
    #pragma unroll
    for (int dg=0; dg<2; ++dg)
      #pragma unroll
      for (int r=0; r<4; r++){
        int qr = q0 + wid*32 + fr*16 + 4*g + r;
        float o = oacc[fr][dg][r] / lrun[fr][r];
        aout[((size_t)b*R_ + qr)*D_ + h*32 + dg*16 + c] = f2b(o);
      }
}

// ---------------- fused residual + layernorm (f32 stream) ----------------
__global__ __launch_bounds__(256) void resid_ln(const float* __restrict__ xin,
    const float* __restrict__ res, const float* __restrict__ gg, const float* __restrict__ bb,
    float* __restrict__ xout, unsigned short* __restrict__ xbf)
{
  int row = blockIdx.x*4 + (threadIdx.x >> 6);
  int lane = threadIdx.x & 63;
  size_t base = (size_t)row*D_ + lane*4;
  float4 a  = *(const float4*)&xin[base];
  float4 rr = *(const float4*)&res[base];
  float y0 = a.x+rr.x, y1 = a.y+rr.y, y2 = a.z+rr.z, y3 = a.w+rr.w;
  float s = y0+y1+y2+y3;
  #pragma unroll
  for (int off=32; off>=1; off>>=1) s += __shfl_xor(s, off);
  float mu = s * (1.0f/256.0f);
  float d0=y0-mu, d1=y1-mu, d2=y2-mu, d3=y3-mu;
  float q = d0*d0 + d1*d1 + d2*d2 + d3*d3;
  #pragma unroll
  for (int off=32; off>=1; off>>=1) q += __shfl_xor(q, off);
  float rstd = rsqrtf(q*(1.0f/256.0f) + 1e-5f);
  float4 gv = *(const float4*)&gg[lane*4];
  float4 bv = *(const float4*)&bb[lane*4];
  float o0 = d0*rstd*gv.x + bv.x;
  float o1 = d1*rstd*gv.y + bv.y;
  float o2 = d2*rstd*gv.z + bv.z;
  float o3 = d3*rstd*gv.w + bv.w;
  float4 o; o.x=o0; o.y=o1; o.z=o2; o.w=o3;
  *(float4*)&xout[base] = o;
  ushort4 ob; ob.x=f2b(o0); ob.y=f2b(o1); ob.z=f2b(o2); ob.w=f2b(o3);
  *(ushort4*)&xbf[base] = ob;
}

// ---------------- driver ----------------
extern "C" void kernel_launch(void* const* d_in, const int* in_sizes, int n_in,
                              void* d_out, int out_size, void* d_ws, size_t ws_size,
                              hipStream_t stream)
{
  const float* node = (const float*)d_in[0];
  const int*   ei   = (const int*)d_in[1];
  const int*   rid  = (const int*)d_in[2];
  const unsigned char* km = (const unsigned char*)d_in[3];
  const float* rb   = (const float*)d_in[4];
  const float* Wqkv = (const float*)d_in[5];
  const float* bqkv = (const float*)d_in[6];
  const float* Wo   = (const float*)d_in[7];
  const float* bo   = (const float*)d_in[8];
  const float* ln1g = (const float*)d_in[9];
  const float* ln1b = (const float*)d_in[10];
  const float* W1   = (const float*)d_in[11];
  const float* b1   = (const float*)d_in[12];
  const float* W2   = (const float*)d_in[13];
  const float* b2   = (const float*)d_in[14];
  const float* ln2g = (const float*)d_in[15];
  const float* ln2b = (const float*)d_in[16];

  char* ws = (char*)d_ws;
  int*   flag = (int*)ws;                                    // 4 B (256 reserved)
  float* mask = (float*)(ws + 256);                          // 33,554,432 B
  unsigned short* wqkv_b = (unsigned short*)(ws + 33554688); //    786,432 B
  unsigned short* wo_b   = (unsigned short*)(ws + 34341120); //    262,144 B
  unsigned short* w1_b   = (unsigned short*)(ws + 34603264); //  1,048,576 B
  unsigned short* w2_b   = (unsigned short*)(ws + 35651840); //  1,048,576 B
  unsigned short* x_bf   = (unsigned short*)(ws + 36700416); //  4,194,304 B
  unsigned short* qkvb   = (unsigned short*)(ws + 40894720); // 12,582,912 B
  unsigned short* ao     = (unsigned short*)(ws + 53477632); //  4,194,304 B
  float* xf   = (float*)(ws + 57671936);                     //  8,388,608 B
  float* tmp  = (float*)(ws + 66060544);                     //  8,388,608 B
  unsigned short* hbuf   = (unsigned short*)(ws + 74449152); // 16,777,216 B  (end ~91.2 MB)

  hipMemsetAsync(flag, 0, 4, stream);
  detect_bool<<<1024, 256, 0, stream>>>(km, flag);
  mask_fill<<<8192, 256, 0, stream>>>(mask);
  edge_base<<<1024, 256, 0, stream>>>(ei, km, flag, mask);
  edge_bias<<<1024, 256, 0, stream>>>(ei, rid, km, flag, rb, mask);

  cvt_bf16<<<384, 256, 0, stream>>>(Wqkv, wqkv_b, L_*768*256);
  cvt_bf16<<<128, 256, 0, stream>>>(Wo,   wo_b,   L_*256*256);
  cvt_bf16<<<512, 256, 0, stream>>>(W1,   w1_b,   L_*1024*256);
  cvt_bf16<<<512, 256, 0, stream>>>(W2,   w2_b,   L_*256*1024);
  cvt_bf16<<<2048,256, 0, stream>>>(node, x_bf,   B_*R_*D_);

  for (int l = 0; l < L_; ++l){
    gemm_bt<0><<<384, 256, 0, stream>>>(x_bf, wqkv_b + l*196608, bqkv + l*768, qkvb, 8192, 768, 256);
    attn_kernel<<<512, 256, 0, stream>>>(qkvb, mask, ao);
    gemm_bt<1><<<128, 256, 0, stream>>>(ao, wo_b + l*65536, bo + l*256, tmp, 8192, 256, 256);
    resid_ln<<<2048, 256, 0, stream>>>(l==0 ? node : xf, tmp, ln1g + l*256, ln1b + l*256, xf, x_bf);
    gemm_bt<2><<<512, 256, 0, stream>>>(x_bf, w1_b + l*262144, b1 + l*1024, hbuf, 8192, 1024, 256);
    gemm_bt<1><<<128, 256, 0, stream>>>(hbuf, w2_b + l*262144, b2 + l*256, tmp, 8192, 256, 1024);
    float* outp = (l == L_-1) ? (float*)d_out : xf;
    resid_ln<<<2048, 256, 0, stream>>>(xf, tmp, ln2g + l*256, ln2b + l*256, outp, x_bf);
  }
}

// Round 5
// 341.652 us; speedup vs baseline: 1.0800x; 1.0800x over previous
//
#include <hip/hip_runtime.h>
#include <hip/hip_bf16.h>
#include <math.h>

#define B_ 8
#define R_ 1024
#define D_ 256
#define H_ 8
#define L_ 2
#define E_ 32768
#define FF_ 1024
#define NEGV (-1000000000.0f)

typedef short bf16x8 __attribute__((ext_vector_type(8)));
typedef float f32x4 __attribute__((ext_vector_type(4)));

__device__ __forceinline__ unsigned short f2b(float f){
  unsigned int u = __float_as_uint(f);
  u += 0x7fffu + ((u >> 16) & 1u);
  return (unsigned short)(u >> 16);
}

__device__ __forceinline__ unsigned int pk_bf16(float lo, float hi){
  unsigned int r;
  asm volatile("v_cvt_pk_bf16_f32 %0, %1, %2" : "=v"(r) : "v"(lo), "v"(hi));
  return r;
}

#define ASYNC_COPY16(gp, lp) \
  __builtin_amdgcn_global_load_lds((const __attribute__((address_space(1))) void*)(gp), \
                                   (__attribute__((address_space(3))) void*)(lp), 16, 0, 0)

// ---------------- mask construction ----------------

__global__ void detect_bool(const unsigned char* __restrict__ km, int* __restrict__ flag){
  int i = blockIdx.x*256 + threadIdx.x;
  int hit = ((i & 3) != 0) && (km[i] != 0);
  if (__ballot(hit) != 0ull && (threadIdx.x & 63) == 0) atomicOr(flag, 1);
}

__global__ void mask_fill(float* __restrict__ mask){
  size_t i = ((size_t)blockIdx.x*256 + threadIdx.x)*4;
  int row = (int)((i >> 10) & 1023);
  int col = (int)(i & 1023);
  float4 v;
  v.x = (row == col+0) ? 0.0f : NEGV;
  v.y = (row == col+1) ? 0.0f : NEGV;
  v.z = (row == col+2) ? 0.0f : NEGV;
  v.w = (row == col+3) ? 0.0f : NEGV;
  *(float4*)&mask[i] = v;
}

__device__ __forceinline__ int keep_of(const unsigned char* km, const int* flag, int tid){
  return flag[0] ? (int)km[tid] : (int)km[(size_t)tid*4];
}

__global__ void edge_base(const int* __restrict__ ei, const unsigned char* __restrict__ km,
                          const int* __restrict__ flag, float* __restrict__ mask){
  int tid = blockIdx.x*256 + threadIdx.x;
  int b = tid >> 15, e = tid & (E_-1);
  if (keep_of(km, flag, tid)){
    int src = ei[(size_t)b*2*E_ + e];
    int dst = ei[(size_t)b*2*E_ + E_ + e];
    mask[((size_t)b*R_ + src)*R_ + dst] = 0.0f;
  }
}

__global__ void edge_bias(const int* __restrict__ ei, const int* __restrict__ rid,
                          const unsigned char* __restrict__ km, const int* __restrict__ flag,
                          const float* __restrict__ rb, float* __restrict__ mask){
  int tid = blockIdx.x*256 + threadIdx.x;
  int b = tid >> 15, e = tid & (E_-1);
  if (keep_of(km, flag, tid)){
    int src = ei[(size_t)b*2*E_ + e];
    int dst = ei[(size_t)b*2*E_ + E_ + e];
    atomicAdd(&mask[((size_t)b*R_ + src)*R_ + dst], rb[rid[tid]]);
  }
}

// ---------------- dtype convert ----------------

__global__ void cvt_bf16(const float* __restrict__ src, unsigned short* __restrict__ dst, int n){
  int i = (blockIdx.x*256 + threadIdx.x)*4;
  if (i >= n) return;
  float4 v = *(const float4*)&src[i];
  ushort4 o;
  o.x = f2b(v.x); o.y = f2b(v.y); o.z = f2b(v.z); o.w = f2b(v.w);
  *(ushort4*)&dst[i] = o;
}

// ---------------- GEMM: C[M,N] = A[M,K] * B[N,K]^T ----------------
// MODE 0: bf16 out +bias | MODE 1: f32 out +bias | MODE 2: bf16 out gelu(+bias)
// BN: 128 (wave tile 64x64) or 64 (wave tile 64x32; grid 2x wider for small N)
template<int MODE, int BN>
__global__ __launch_bounds__(256) void gemm_bt(const unsigned short* __restrict__ A,
    const unsigned short* __restrict__ Bw, const float* __restrict__ bias,
    void* __restrict__ Cout, int M, int N, int K)
{
  constexpr int NI = BN/32;          // B-frags per wave
  constexpr int NCH = 8 + BN/16;     // 512-short staging chunks
  constexpr int CPW = NCH/4;         // chunks per wave
  __shared__ unsigned short As[128*32];
  __shared__ unsigned short Bs[BN*32];
  const int nb = N / BN;
  const int bm = blockIdx.x / nb, bn = blockIdx.x % nb;
  const int m0 = bm << 7, n0 = bn * BN;
  const int t = threadIdx.x, lane = t & 63, wid = t >> 6;
  const int wr = wid >> 1, wc = wid & 1;
  const int c = lane & 15, g = lane >> 4;

  f32x4 zz = {0.f,0.f,0.f,0.f};
  f32x4 acc[4][NI];
  #pragma unroll
  for (int mi=0; mi<4; mi++)
    #pragma unroll
    for (int ni=0; ni<NI; ni++) acc[mi][ni] = zz;

  for (int k0 = 0; k0 < K; k0 += 32){
    __syncthreads();
    #pragma unroll
    for (int it=0; it<CPW; ++it){
      int chunk = wid*CPW + it;            // wave-uniform
      int row16 = lane >> 2, seg = lane & 3;
      if (chunk < 8){
        int row = chunk*16 + row16;
        ASYNC_COPY16(A + (size_t)(m0+row)*K + k0 + seg*8, &As[chunk*512]);
      } else {
        int bch = chunk - 8;
        int row = bch*16 + row16;
        ASYNC_COPY16(Bw + (size_t)(n0+row)*K + k0 + seg*8, &Bs[bch*512]);
      }
    }
    __syncthreads();
    bf16x8 af[4], bfr[NI];
    #pragma unroll
    for (int mi=0; mi<4; mi++) af[mi]  = *(const bf16x8*)&As[(wr*64 + mi*16 + c)*32 + g*8];
    #pragma unroll
    for (int ni=0; ni<NI; ni++) bfr[ni] = *(const bf16x8*)&Bs[(wc*(BN/2) + ni*16 + c)*32 + g*8];
    #pragma unroll
    for (int mi=0; mi<4; mi++)
      #pragma unroll
      for (int ni=0; ni<NI; ni++)
        acc[mi][ni] = __builtin_amdgcn_mfma_f32_16x16x32_bf16(af[mi], bfr[ni], acc[mi][ni], 0,0,0);
  }

  #pragma unroll
  for (int mi=0; mi<4; mi++){
    #pragma unroll
    for (int ni=0; ni<NI; ni++){
      int col = n0 + wc*(BN/2) + ni*16 + c;
      float bv = bias[col];
      #pragma unroll
      for (int r=0; r<4; r++){
        int row = m0 + wr*64 + mi*16 + 4*g + r;
        float v = acc[mi][ni][r] + bv;
        if (MODE == 2) v = 0.5f*v*(1.0f + erff(v*0.70710678f));
        if (MODE == 1) ((float*)Cout)[(size_t)row*N + col] = v;
        else           ((unsigned short*)Cout)[(size_t)row*N + col] = f2b(v);
      }
    }
  }
}

// ---------------- fused flash attention v2 (swapped operands, no P-LDS) ----------
// 512 blocks x 512 threads (8 waves). Wave w owns q rows qt*128 + w*16 + c.
// S^T = mfma(K,Q): lane (c,g) holds S[q=qrow][kv=16fc+4g+r] -> softmax lane-local in q.
// PV as O^T = mfma(V^T, P): alpha/l rescale lane-local; P A-frag built via shuffles.
__global__ __launch_bounds__(512, 4) void attn_kernel(const unsigned short* __restrict__ qkv,
    const float* __restrict__ mask, unsigned short* __restrict__ aout)
{
  __shared__ unsigned short Klds[128*40];   // K tile [kv][d], row stride 40
  __shared__ unsigned short VT[32*136];     // V^T tile [d][kv], row stride 136
  const int blk = blockIdx.x;
  const int qt = blk & 7, h = (blk >> 3) & 7, b = blk >> 6;
  const int t = threadIdx.x, lane = t & 63, w = t >> 6;
  const int c = lane & 15, g = lane >> 4;
  const int qrow = qt*128 + w*16 + c;
  const size_t qbase = (size_t)b*R_*768;
  const float scale = 0.17677669529663689f;   // 1/sqrt(32)

  // Q fragment: Q[qrow][d=8g..8g+7] (B-operand for QK^T)
  bf16x8 qf = *(const bf16x8*)&qkv[qbase + (size_t)qrow*768 + h*32 + g*8];

  f32x4 z4 = {0.f,0.f,0.f,0.f};
  f32x4 oacc[2] = {z4, z4};       // oacc[dg][r] = O[qrow][h*32+dg*16+4g+r] (pre-normalize)
  float mrun = -1e30f, lrun = 0.f;

  const int srcA = c + ((lane & 16) << 1);   // c + 32*(g&1)
  const int srcB = srcA + 16;
  const bool hig = (lane >= 32);             // g>=2 -> odd fc

  for (int kt=0; kt<8; ++kt){
    const int kv0 = kt*128;
    __syncthreads();
    { // stage K: one uint4 per thread
      int row = t >> 2, seg = t & 3;
      uint4 kd = *(const uint4*)&qkv[qbase + (size_t)(kv0+row)*768 + 256 + h*32 + seg*8];
      *(uint4*)&Klds[row*40 + seg*8] = kd;
    }
    { // stage V transposed: 8 scalar loads + 1 uint4 write per thread
      int d = t & 31, grp = t >> 5;
      __align__(16) unsigned short tv[8];
      #pragma unroll
      for (int j=0; j<8; j++)
        tv[j] = qkv[qbase + (size_t)(kv0 + grp*8 + j)*768 + 512 + h*32 + d];
      *(uint4*)&VT[d*136 + grp*8] = *(const uint4*)&tv[0];
    }
    __syncthreads();

    // S^T: st[fc][r] = S[qrow][kv0 + 16fc + 4g + r]
    f32x4 st[8];
    #pragma unroll
    for (int fc=0; fc<8; ++fc){
      bf16x8 kb = *(const bf16x8*)&Klds[(fc*16 + c)*40 + g*8];
      st[fc] = __builtin_amdgcn_mfma_f32_16x16x32_bf16(kb, qf, z4, 0,0,0);
    }
    // scale + mask (vectorized over r)
    const float* mrow = &mask[((size_t)b*R_ + qrow)*R_ + kv0];
    #pragma unroll
    for (int fc=0; fc<8; ++fc){
      float4 mv = *(const float4*)&mrow[fc*16 + 4*g];
      st[fc][0] = st[fc][0]*scale + mv.x;
      st[fc][1] = st[fc][1]*scale + mv.y;
      st[fc][2] = st[fc][2]*scale + mv.z;
      st[fc][3] = st[fc][3]*scale + mv.w;
    }
    // online softmax, q fixed per lane: reduce over 32 regs then 4 g-lanes
    float mx = st[0][0];
    #pragma unroll
    for (int fc=0; fc<8; ++fc)
      #pragma unroll
      for (int r=0; r<4; r++) mx = fmaxf(mx, st[fc][r]);
    mx = fmaxf(mx, __shfl_xor(mx, 16));
    mx = fmaxf(mx, __shfl_xor(mx, 32));
    float mnew  = fmaxf(mrun, mx);
    float alpha = __expf(mrun - mnew);
    float sum = 0.f;
    #pragma unroll
    for (int fc=0; fc<8; ++fc)
      #pragma unroll
      for (int r=0; r<4; r++){
        float pv = __expf(st[fc][r] - mnew);
        st[fc][r] = pv;
        sum += pv;
      }
    sum += __shfl_xor(sum, 16);
    sum += __shfl_xor(sum, 32);
    lrun = lrun*alpha + sum;
    mrun = mnew;
    oacc[0][0]*=alpha; oacc[0][1]*=alpha; oacc[0][2]*=alpha; oacc[0][3]*=alpha;
    oacc[1][0]*=alpha; oacc[1][1]*=alpha; oacc[1][2]*=alpha; oacc[1][3]*=alpha;

    // pack P to bf16 pairs: u0[fc]=(kv 16fc+4g, +1), u1[fc]=(+2, +3)
    unsigned int u0[8], u1[8];
    #pragma unroll
    for (int fc=0; fc<8; ++fc){
      u0[fc] = pk_bf16(st[fc][0], st[fc][1]);
      u1[fc] = pk_bf16(st[fc][2], st[fc][3]);
    }

    // PV: for each ks, build P A-frag (lane (c,g): P[q=c-row][kv=32ks+8g..+7]) by shuffle
    #pragma unroll
    for (int ks=0; ks<4; ++ks){
      unsigned int e0 = u0[2*ks],   e1 = u1[2*ks];
      unsigned int o0 = u0[2*ks+1], o1 = u1[2*ks+1];
      unsigned int w0e = __shfl((int)e0, srcA), w1e = __shfl((int)e1, srcA);
      unsigned int w2e = __shfl((int)e0, srcB), w3e = __shfl((int)e1, srcB);
      unsigned int w0o = __shfl((int)o0, srcA), w1o = __shfl((int)o1, srcA);
      unsigned int w2o = __shfl((int)o0, srcB), w3o = __shfl((int)o1, srcB);
      union { unsigned int u[4]; bf16x8 v; } pa;
      pa.u[0] = hig ? w0o : w0e;
      pa.u[1] = hig ? w1o : w1e;
      pa.u[2] = hig ? w2o : w2e;
      pa.u[3] = hig ? w3o : w3e;
      #pragma unroll
      for (int dg=0; dg<2; ++dg){
        bf16x8 vb = *(const bf16x8*)&VT[(dg*16 + c)*136 + ks*32 + g*8];
        oacc[dg] = __builtin_amdgcn_mfma_f32_16x16x32_bf16(vb, pa.v, oacc[dg], 0,0,0);
      }
    }
  }
  // epilogue: O[qrow][h*32 + dg*16 + 4g + r] — lane-local l
  float rl = 1.0f / lrun;
  #pragma unroll
  for (int dg=0; dg<2; ++dg){
    unsigned int p0 = pk_bf16(oacc[dg][0]*rl, oacc[dg][1]*rl);
    unsigned int p1 = pk_bf16(oacc[dg][2]*rl, oacc[dg][3]*rl);
    size_t base = ((size_t)b*R_ + qrow)*D_ + h*32 + dg*16 + 4*g;
    uint2 pp; pp.x = p0; pp.y = p1;
    *(uint2*)&aout[base] = pp;
  }
}

// ---------------- fused residual + layernorm ----------------
__global__ __launch_bounds__(256) void resid_ln(const float* __restrict__ xin,
    const float* __restrict__ res, const float* __restrict__ gg, const float* __restrict__ bb,
    float* __restrict__ xout, unsigned short* __restrict__ xbf)
{
  int row = blockIdx.x*4 + (threadIdx.x >> 6);
  int lane = threadIdx.x & 63;
  size_t base = (size_t)row*D_ + lane*4;
  float4 a  = *(const float4*)&xin[base];
  float4 rr = *(const float4*)&res[base];
  float y0 = a.x+rr.x, y1 = a.y+rr.y, y2 = a.z+rr.z, y3 = a.w+rr.w;
  float s = y0+y1+y2+y3;
  #pragma unroll
  for (int off=32; off>=1; off>>=1) s += __shfl_xor(s, off);
  float mu = s * (1.0f/256.0f);
  float d0=y0-mu, d1=y1-mu, d2=y2-mu, d3=y3-mu;
  float q = d0*d0 + d1*d1 + d2*d2 + d3*d3;
  #pragma unroll
  for (int off=32; off>=1; off>>=1) q += __shfl_xor(q, off);
  float rstd = rsqrtf(q*(1.0f/256.0f) + 1e-5f);
  float4 gv = *(const float4*)&gg[lane*4];
  float4 bv = *(const float4*)&bb[lane*4];
  float o0 = d0*rstd*gv.x + bv.x;
  float o1 = d1*rstd*gv.y + bv.y;
  float o2 = d2*rstd*gv.z + bv.z;
  float o3 = d3*rstd*gv.w + bv.w;
  float4 o; o.x=o0; o.y=o1; o.z=o2; o.w=o3;
  *(float4*)&xout[base] = o;
  ushort4 ob; ob.x=f2b(o0); ob.y=f2b(o1); ob.z=f2b(o2); ob.w=f2b(o3);
  *(ushort4*)&xbf[base] = ob;
}

// ---------------- driver ----------------
extern "C" void kernel_launch(void* const* d_in, const int* in_sizes, int n_in,
                              void* d_out, int out_size, void* d_ws, size_t ws_size,
                              hipStream_t stream)
{
  const float* node = (const float*)d_in[0];
  const int*   ei   = (const int*)d_in[1];
  const int*   rid  = (const int*)d_in[2];
  const unsigned char* km = (const unsigned char*)d_in[3];
  const float* rb   = (const float*)d_in[4];
  const float* Wqkv = (const float*)d_in[5];
  const float* bqkv = (const float*)d_in[6];
  const float* Wo   = (const float*)d_in[7];
  const float* bo   = (const float*)d_in[8];
  const float* ln1g = (const float*)d_in[9];
  const float* ln1b = (const float*)d_in[10];
  const float* W1   = (const float*)d_in[11];
  const float* b1   = (const float*)d_in[12];
  const float* W2   = (const float*)d_in[13];
  const float* b2   = (const float*)d_in[14];
  const float* ln2g = (const float*)d_in[15];
  const float* ln2b = (const float*)d_in[16];

  char* ws = (char*)d_ws;
  int*   flag = (int*)ws;
  float* mask = (float*)(ws + 256);
  unsigned short* wqkv_b = (unsigned short*)(ws + 33554688);
  unsigned short* wo_b   = (unsigned short*)(ws + 34341120);
  unsigned short* w1_b   = (unsigned short*)(ws + 34603264);
  unsigned short* w2_b   = (unsigned short*)(ws + 35651840);
  unsigned short* x_bf   = (unsigned short*)(ws + 36700416);
  unsigned short* qkvb   = (unsigned short*)(ws + 40894720);
  unsigned short* ao     = (unsigned short*)(ws + 53477632);
  float* xf   = (float*)(ws + 57671936);
  float* tmp  = (float*)(ws + 66060544);
  unsigned short* hbuf   = (unsigned short*)(ws + 74449152);

  hipMemsetAsync(flag, 0, 4, stream);
  detect_bool<<<1024, 256, 0, stream>>>(km, flag);
  mask_fill<<<8192, 256, 0, stream>>>(mask);
  edge_base<<<1024, 256, 0, stream>>>(ei, km, flag, mask);
  edge_bias<<<1024, 256, 0, stream>>>(ei, rid, km, flag, rb, mask);

  cvt_bf16<<<384, 256, 0, stream>>>(Wqkv, wqkv_b, L_*768*256);
  cvt_bf16<<<128, 256, 0, stream>>>(Wo,   wo_b,   L_*256*256);
  cvt_bf16<<<512, 256, 0, stream>>>(W1,   w1_b,   L_*1024*256);
  cvt_bf16<<<512, 256, 0, stream>>>(W2,   w2_b,   L_*256*1024);
  cvt_bf16<<<2048,256, 0, stream>>>(node, x_bf,   B_*R_*D_);

  for (int l = 0; l < L_; ++l){
    gemm_bt<0,128><<<384, 256, 0, stream>>>(x_bf, wqkv_b + l*196608, bqkv + l*768, qkvb, 8192, 768, 256);
    attn_kernel<<<512, 512, 0, stream>>>(qkvb, mask, ao);
    gemm_bt<1,64><<<256, 256, 0, stream>>>(ao, wo_b + l*65536, bo + l*256, tmp, 8192, 256, 256);
    resid_ln<<<2048, 256, 0, stream>>>(l==0 ? node : xf, tmp, ln1g + l*256, ln1b + l*256, xf, x_bf);
    gemm_bt<2,128><<<512, 256, 0, stream>>>(x_bf, w1_b + l*262144, b1 + l*1024, hbuf, 8192, 1024, 256);
    gemm_bt<1,64><<<256, 256, 0, stream>>>(hbuf, w2_b + l*262144, b2 + l*256, tmp, 8192, 256, 1024);
    float* outp = (l == L_-1) ? (float*)d_out : xf;
    resid_ln<<<2048, 256, 0, stream>>>(xf, tmp, ln2g + l*256, ln2b + l*256, outp, x_bf);
  }
}